// Round 16
// baseline (456.470 us; speedup 1.0000x reference)
//
#include <hip/hip_runtime.h>

#define NN 100000
#define BQ 1024
#define EE 262144
#define KTOP 20

typedef unsigned long long ull;
typedef __attribute__((ext_vector_type(8))) short bf16x8;
typedef __attribute__((ext_vector_type(4))) float f32x4;

__device__ __forceinline__ ull enc64(double d) {
  ull u = (ull)__double_as_longlong(d);
  return (u >> 63) ? ~u : (u | 0x8000000000000000ull);
}
__device__ __forceinline__ double dec64(ull u) {
  ull b = (u >> 63) ? (u & 0x7FFFFFFFFFFFFFFFull) : ~u;
  return __longlong_as_double((long long)b);
}

__device__ __forceinline__ unsigned short f2bf(float f) {
  unsigned u = __float_as_uint(f);
  u += 0x7fff + ((u >> 16) & 1);
  return (unsigned short)(u >> 16);
}
__device__ __forceinline__ float bf2f(unsigned short h) {
  return __uint_as_float(((unsigned)h) << 16);
}
__device__ __forceinline__ void cvt8(float4 x, float4 y, bf16x8& hi, bf16x8& lo) {
  float a[8] = {x.x, x.y, x.z, x.w, y.x, y.y, y.z, y.w};
#pragma unroll
  for (int j = 0; j < 8; j++) {
    unsigned short h = f2bf(a[j]);
    float r = a[j] - bf2f(h);
    hi[j] = (short)h;
    lo[j] = (short)f2bf(r);
  }
}

// ---------------- init + edge pack (merged) ----------------
__global__ void k_prep(const int* __restrict__ edges, int4* __restrict__ evi,
                       int* __restrict__ vi32, ull* __restrict__ menc,
                       double* __restrict__ s, float* __restrict__ appears,
                       float* __restrict__ out_score) {
  int i = blockIdx.x * 256 + threadIdx.x;
  int st = gridDim.x * 256;
  for (int e = i; e < EE; e += st) {
    int vi = edges[(size_t)e * 8 + 6];
    evi[e] = make_int4(edges[(size_t)e * 8 + 0], vi, edges[(size_t)e * 8 + 7], 0);
    vi32[e] = vi;
  }
  for (int n = i; n < NN; n += st) {
    menc[n] = 0ull;
    s[n] = 0.0;
    appears[n] = 0.f;
    out_score[n] = 0.f;
  }
}

// ---------------- M = Wq^T Wk (f32) + transpose fused ----------------
__global__ void k_matM(const float* __restrict__ Wq, const float* __restrict__ Wk,
                       float* __restrict__ M, float* __restrict__ MT) {
  int x = blockIdx.x;
  int y = blockIdx.y * 256 + threadIdx.x;
  float acc = 0.f;
  for (int a = 0; a < 512; a++)
    acc += Wq[a * 512 + x] * Wk[a * 512 + y];
  M[x * 512 + y] = acc;
  MT[y * 512 + x] = acc;
}

// ---------------- pack B operands as bf16 hi/lo in FRAGMENT ORDER ----------------
__global__ void k_pack(const float* __restrict__ M, const float* __restrict__ MT,
                       const float* __restrict__ Wl,
                       short* __restrict__ wn_hi, short* __restrict__ wn_lo,
                       short* __restrict__ m11_hi, short* __restrict__ m11_lo,
                       short* __restrict__ wl_hi, short* __restrict__ wl_lo) {
  int idx = blockIdx.x * 256 + threadIdx.x;
  if (idx >= 5 * 16384) return;
  int arr = idx >> 14;
  int j16 = idx & 16383;
  int g = j16 >> 9;
  int l = (j16 >> 3) & 63;
  int jj = j16 & 7;
  int c = (g >> 2) * 16 + (l & 15);
  int k = (g & 3) * 32 + ((l >> 4) << 3) + jj;
  float v;
  short *dh, *dl;
  if (arr == 0)      { v = MT[(size_t)c * 512 + k];               dh = wn_hi;          dl = wn_lo; }
  else if (arr == 1) { v = MT[(size_t)(128 + c) * 512 + k];       dh = wn_hi + 16384;  dl = wn_lo + 16384; }
  else if (arr == 2) { v = M[(size_t)(128 + c) * 512 + k];        dh = wn_hi + 32768;  dl = wn_lo + 32768; }
  else if (arr == 3) { v = MT[(size_t)(128 + c) * 512 + 128 + k]; dh = m11_hi;         dl = m11_lo; }
  else               { v = Wl[(size_t)c * 128 + k];               dh = wl_hi;          dl = wl_lo; }
  unsigned short h = f2bf(v);
  float r = v - bf2f(h);
  dh[j16] = (short)h;
  dl[j16] = (short)f2bf(r);
}

// ---------------- per-query vectors (f32) ----------------
__global__ void k_pq(const float* __restrict__ M, const float* __restrict__ MT,
                     const float* __restrict__ qsA, const float* __restrict__ qrA,
                     float* __restrict__ Qv, double* __restrict__ cq) {
  int b = blockIdx.x, d = threadIdx.x;  // 128 threads
  __shared__ float qs[128], qr[128];
  qs[d] = qsA[b * 128 + d];
  qr[d] = qrA[b * 128 + d];
  __syncthreads();
  float uh = 0, ui = 0, ur = 0;
  for (int x = 0; x < 128; x++) {
    float qsx = qs[x], qrx = qr[x];
    uh += qsx * M[(256 + x) * 512 + d]        + qrx * M[(384 + x) * 512 + d];
    ur += qsx * M[(256 + x) * 512 + 128 + d]  + qrx * M[(384 + x) * 512 + 128 + d];
    ui += qsx * MT[(256 + x) * 512 + d]       + qrx * MT[(384 + x) * 512 + d];
    ur += qsx * MT[(256 + x) * 512 + 128 + d] + qrx * MT[(384 + x) * 512 + 128 + d];
  }
  Qv[b * 384 + d]       = uh;
  Qv[b * 384 + 128 + d] = ui;
  Qv[b * 384 + 256 + d] = ur;
  float t1 = 0, t2 = 0;
  for (int y = 0; y < 128; y++) {
    float qsy = qs[y], qry = qr[y];
    t1 += qsy * MT[(256 + y) * 512 + 256 + d] + qry * MT[(384 + y) * 512 + 256 + d];
    t2 += qsy * MT[(256 + y) * 512 + 384 + d] + qry * MT[(384 + y) * 512 + 384 + d];
  }
  float cp = qs[d] * t1 + qr[d] * t2;
  for (int off = 32; off; off >>= 1) cp += __shfl_down(cp, off, 64);
  __shared__ float red[2];
  if ((d & 63) == 0) red[d >> 6] = cp;
  __syncthreads();
  if (d == 0) cq[b] = (double)(red[0] + red[1]);
}

// ---------------- node transforms -> PV[n][384]=[G|H1|nrep], J[n][128] ----------------
__global__ __launch_bounds__(512) void k_gemm_node(const float* __restrict__ A,
                                                   const short* __restrict__ WT_hi,
                                                   const short* __restrict__ WT_lo,
                                                   float* __restrict__ PV,
                                                   float* __restrict__ J) {
  __shared__ __align__(16) float As[64][132];
  __shared__ __align__(16) short Bh[16384];
  float* Of = (float*)Bh;  // output staging view [64][128]
  int t = threadIdx.x;
  int row0 = blockIdx.x * 64;
  int w = t >> 6, l = t & 63;
  int rt = w & 3;
  int c0 = (w >> 2) * 4;
#pragma unroll
  for (int i = 0; i < 4; i++) {
    int fi = t + i * 512;
    int r = fi >> 5, c4 = (fi & 31) * 4;
    float4 v = make_float4(0.f, 0.f, 0.f, 0.f);
    if (row0 + r < NN) v = *(const float4*)(A + (size_t)(row0 + r) * 128 + c4);
    *(float4*)&As[r][c4] = v;
    *(bf16x8*)&Bh[fi * 8] = *(const bf16x8*)(WT_hi + fi * 8);
  }
  __syncthreads();
  int rloc = rt * 16 + (l & 15);
  int kq = (l >> 4) * 8;
  for (int panel = 0; panel < 3; panel++) {
    const short* sl = WT_lo + panel * 16384;
    bf16x8 blv[4][4];
#pragma unroll
    for (int cc = 0; cc < 4; cc++)
#pragma unroll
      for (int kt = 0; kt < 4; kt++)
        blv[cc][kt] = *(const bf16x8*)(sl + (((c0 + cc) * 4 + kt) * 64 + l) * 8);
    f32x4 acc[4];
#pragma unroll
    for (int cc = 0; cc < 4; cc++)
#pragma unroll
      for (int j = 0; j < 4; j++) acc[cc][j] = 0.f;
#pragma unroll
    for (int kt = 0; kt < 4; kt++) {
      int kb = kt * 32 + kq;
      float4 x = *(const float4*)&As[rloc][kb];
      float4 y = *(const float4*)&As[rloc][kb + 4];
      bf16x8 ah, al;
      cvt8(x, y, ah, al);
#pragma unroll
      for (int cc = 0; cc < 4; cc++) {
        int off = (((cc + c0) * 4 + kt) * 64 + l) * 8;
        bf16x8 bhv = *(const bf16x8*)&Bh[off];
        acc[cc] = __builtin_amdgcn_mfma_f32_16x16x32_bf16(ah, bhv, acc[cc], 0, 0, 0);
        acc[cc] = __builtin_amdgcn_mfma_f32_16x16x32_bf16(al, bhv, acc[cc], 0, 0, 0);
        acc[cc] = __builtin_amdgcn_mfma_f32_16x16x32_bf16(ah, blv[cc][kt], acc[cc], 0, 0, 0);
      }
    }
    __syncthreads();
#pragma unroll
    for (int cc = 0; cc < 4; cc++) {
      int col = (c0 + cc) * 16 + (l & 15);
#pragma unroll
      for (int reg = 0; reg < 4; reg++)
        Of[(rt * 16 + (l >> 4) * 4 + reg) * 128 + col] = acc[cc][reg];
    }
    __syncthreads();
#pragma unroll
    for (int i = 0; i < 4; i++) {
      int fi = t + i * 512;
      int r = fi >> 5, c4 = (fi & 31) * 4;
      int rr = row0 + r;
      if (rr < NN) {
        float4 v = *(float4*)&Of[r * 128 + c4];
        if (panel == 0)      *(float4*)&PV[(size_t)rr * 384 + c4] = v;
        else if (panel == 1) *(float4*)&PV[(size_t)rr * 384 + 128 + c4] = v;
        else                 *(float4*)&J[(size_t)rr * 128 + c4] = v;
      }
    }
    if (panel < 2) {
      __syncthreads();
      const short* sh = WT_hi + (panel + 1) * 16384;
#pragma unroll
      for (int i = 0; i < 4; i++) {
        int fi = t + i * 512;
        *(bf16x8*)&Bh[fi * 8] = *(const bf16x8*)(sh + fi * 8);
      }
      __syncthreads();
    }
  }
  // nrep copy into PV[:,256:384] (As still holds the node_repr tile)
#pragma unroll
  for (int i = 0; i < 4; i++) {
    int fi = t + i * 512;
    int r = fi >> 5, c4 = (fi & 31) * 4;
    int rr = row0 + r;
    if (rr < NN) *(float4*)&PV[(size_t)rr * 384 + 256 + c4] = *(float4*)&As[r][c4];
  }
}

// ---------------- FUSED per-edge kernel: full logit + segment max ----------------
// vi-side data from PV[vi][384]=[G|H1|nrep] (one contiguous gather region)
__global__ __launch_bounds__(512, 1) void k_edge(const float* __restrict__ rel,
                                                 const short* __restrict__ M11T_hi,
                                                 const short* __restrict__ M11T_lo,
                                                 const int4* __restrict__ evi,
                                                 const float* __restrict__ PV,
                                                 const float* __restrict__ J,
                                                 const float* __restrict__ nrep,
                                                 const float* __restrict__ Qv,
                                                 const double* __restrict__ cq,
                                                 double* __restrict__ logits,
                                                 ull* __restrict__ menc) {
  __shared__ __align__(16) float Rs[64][132];
  __shared__ __align__(16) short Bh[16384];
  __shared__ float part[4][64];
  __shared__ float dg[64];
  __shared__ float uhs[128], uis[128], urs[128];
  __shared__ double cqs;
  int t = threadIdx.x;
  int e0 = blockIdx.x * 64;
  int eg = e0 >> 8;  // DEG=256
  int w = t >> 6, l = t & 63;
  int cq2 = w & 3;   // col quarter: col-tiles 2*cq2, 2*cq2+1
  int rh = w >> 2;   // row half: row-tiles 2*rh, 2*rh+1
  // ---- early gather prefetch: H1[vi] (PV+128), J[vj] for 2 edges per 16-lane group ----
  int gg = t >> 4, ll = t & 15, d = ll * 8;
  int4 edA = evi[e0 + gg * 2];
  int4 edB = evi[e0 + gg * 2 + 1];
  const float* pvA = PV + (size_t)edA.y * 384;
  const float* pvB = PV + (size_t)edB.y * 384;
  const float* pA2 = J + (size_t)edA.z * 128 + d;
  const float* pB2 = J + (size_t)edB.z * 128 + d;
  float4 Aa0 = *(const float4*)(pvA + 128 + d), Aa1 = *(const float4*)(pvA + 132 + d);
  float4 Ab0 = *(const float4*)pA2,             Ab1 = *(const float4*)(pA2 + 4);
  float4 Ba0 = *(const float4*)(pvB + 128 + d), Ba1 = *(const float4*)(pvB + 132 + d);
  float4 Bb0 = *(const float4*)pB2,             Bb1 = *(const float4*)(pB2 + 4);
  // ---- B-lo register preload ----
  bf16x8 blv[2][4];
#pragma unroll
  for (int cc = 0; cc < 2; cc++)
#pragma unroll
    for (int kt = 0; kt < 4; kt++)
      blv[cc][kt] = *(const bf16x8*)(M11T_lo + (((cq2 * 2 + cc) * 4 + kt) * 64 + l) * 8);
  // ---- stage Rs + Bh + query vectors ----
#pragma unroll
  for (int i = 0; i < 4; i++) {
    int fi = t + i * 512;
    int r = fi >> 5, c4 = (fi & 31) * 4;
    *(float4*)&Rs[r][c4] = *(const float4*)(rel + (size_t)(e0 + r) * 128 + c4);
    *(bf16x8*)&Bh[fi * 8] = *(const bf16x8*)(M11T_hi + fi * 8);
  }
  if (t < 128) {
    uhs[t] = Qv[(size_t)eg * 384 + t];
    uis[t] = Qv[(size_t)eg * 384 + 128 + t];
    urs[t] = Qv[(size_t)eg * 384 + 256 + t];
  }
  if (t == 0) cqs = cq[eg];
  __syncthreads();
  int kq = (l >> 4) * 8;
  int rq4 = (l >> 4) * 4;
  // ---- MFMA phase: 2 row-tiles sequential, B reused ----
#pragma unroll
  for (int rt2 = 0; rt2 < 2; rt2++) {
    int rt = rh * 2 + rt2;
    int rloc = rt * 16 + (l & 15);
    f32x4 acc[2];
#pragma unroll
    for (int cc = 0; cc < 2; cc++)
#pragma unroll
      for (int j = 0; j < 4; j++) acc[cc][j] = 0.f;
#pragma unroll
    for (int kt = 0; kt < 4; kt++) {
      int kb = kt * 32 + kq;
      float4 x = *(const float4*)&Rs[rloc][kb];
      float4 y = *(const float4*)&Rs[rloc][kb + 4];
      bf16x8 ah, al;
      cvt8(x, y, ah, al);
#pragma unroll
      for (int cc = 0; cc < 2; cc++) {
        bf16x8 bhv = *(const bf16x8*)&Bh[(((cq2 * 2 + cc) * 4 + kt) * 64 + l) * 8];
        acc[cc] = __builtin_amdgcn_mfma_f32_16x16x32_bf16(ah, bhv, acc[cc], 0, 0, 0);
        acc[cc] = __builtin_amdgcn_mfma_f32_16x16x32_bf16(al, bhv, acc[cc], 0, 0, 0);
        acc[cc] = __builtin_amdgcn_mfma_f32_16x16x32_bf16(ah, blv[cc][kt], acc[cc], 0, 0, 0);
      }
    }
    float p[4] = {0.f, 0.f, 0.f, 0.f};
#pragma unroll
    for (int cc = 0; cc < 2; cc++) {
      int c = (cq2 * 2 + cc) * 16 + (l & 15);
#pragma unroll
      for (int reg = 0; reg < 4; reg++)
        p[reg] += acc[cc][reg] * Rs[rt * 16 + rq4 + reg][c];
    }
#pragma unroll
    for (int reg = 0; reg < 4; reg++) {
      p[reg] += __shfl_xor(p[reg], 1, 64);
      p[reg] += __shfl_xor(p[reg], 2, 64);
      p[reg] += __shfl_xor(p[reg], 4, 64);
      p[reg] += __shfl_xor(p[reg], 8, 64);
    }
    if ((l & 15) == 0) {
#pragma unroll
      for (int reg = 0; reg < 4; reg++) part[cq2][rt * 16 + rq4 + reg] = p[reg];
    }
  }
  // ---- dg dots using prefetched H1/J ----
  float4 u0 = *(const float4*)&urs[d], u1 = *(const float4*)&urs[d + 4];
  {
    int le = gg * 2;
    float4 r0 = *(const float4*)&Rs[le][d], r1 = *(const float4*)&Rs[le][d + 4];
    float dot = (Aa0.x + Ab0.x + u0.x) * r0.x + (Aa0.y + Ab0.y + u0.y) * r0.y
              + (Aa0.z + Ab0.z + u0.z) * r0.z + (Aa0.w + Ab0.w + u0.w) * r0.w
              + (Aa1.x + Ab1.x + u1.x) * r1.x + (Aa1.y + Ab1.y + u1.y) * r1.y
              + (Aa1.z + Ab1.z + u1.z) * r1.z + (Aa1.w + Ab1.w + u1.w) * r1.w;
    dot += __shfl_xor(dot, 1, 64);
    dot += __shfl_xor(dot, 2, 64);
    dot += __shfl_xor(dot, 4, 64);
    dot += __shfl_xor(dot, 8, 64);
    if (ll == 0) dg[le] = dot;
  }
  {
    int le = gg * 2 + 1;
    float4 r0 = *(const float4*)&Rs[le][d], r1 = *(const float4*)&Rs[le][d + 4];
    float dot = (Ba0.x + Bb0.x + u0.x) * r0.x + (Ba0.y + Bb0.y + u0.y) * r0.y
              + (Ba0.z + Bb0.z + u0.z) * r0.z + (Ba0.w + Bb0.w + u0.w) * r0.w
              + (Ba1.x + Bb1.x + u1.x) * r1.x + (Ba1.y + Bb1.y + u1.y) * r1.y
              + (Ba1.z + Bb1.z + u1.z) * r1.z + (Ba1.w + Bb1.w + u1.w) * r1.w;
    dot += __shfl_xor(dot, 1, 64);
    dot += __shfl_xor(dot, 2, 64);
    dot += __shfl_xor(dot, 4, 64);
    dot += __shfl_xor(dot, 8, 64);
    if (ll == 0) dg[le] = dot;
  }
  // ---- G/nrep[vi] from PV (contiguous with H1); nrep[vj] separate ----
  float4 GA0 = *(const float4*)(pvA + d),       GA1 = *(const float4*)(pvA + 4 + d);
  float4 IA0 = *(const float4*)(pvA + 256 + d), IA1 = *(const float4*)(pvA + 260 + d);
  const float* jA = nrep + (size_t)edA.z * 128 + d;
  float4 JA0 = *(const float4*)jA, JA1 = *(const float4*)(jA + 4);
  float4 GB0 = *(const float4*)(pvB + d),       GB1 = *(const float4*)(pvB + 4 + d);
  float4 IB0 = *(const float4*)(pvB + 256 + d), IB1 = *(const float4*)(pvB + 260 + d);
  const float* jB = nrep + (size_t)edB.z * 128 + d;
  float4 JB0 = *(const float4*)jB, JB1 = *(const float4*)(jB + 4);
  __syncthreads();
  // ---- final logit assembly ----
  float4 h0 = *(const float4*)&uhs[d], h1 = *(const float4*)&uhs[d + 4];
  float4 i0 = *(const float4*)&uis[d], i1 = *(const float4*)&uis[d + 4];
  {
    int le = gg * 2;
    float gd = (GA0.x + h0.x) * JA0.x + (GA0.y + h0.y) * JA0.y
             + (GA0.z + h0.z) * JA0.z + (GA0.w + h0.w) * JA0.w
             + (GA1.x + h1.x) * JA1.x + (GA1.y + h1.y) * JA1.y
             + (GA1.z + h1.z) * JA1.z + (GA1.w + h1.w) * JA1.w
             + i0.x * IA0.x + i0.y * IA0.y + i0.z * IA0.z + i0.w * IA0.w
             + i1.x * IA1.x + i1.y * IA1.y + i1.z * IA1.z + i1.w * IA1.w;
    gd += __shfl_xor(gd, 1, 64);
    gd += __shfl_xor(gd, 2, 64);
    gd += __shfl_xor(gd, 4, 64);
    gd += __shfl_xor(gd, 8, 64);
    if (ll == 0) {
      float base = ((part[0][le] + part[1][le]) + (part[2][le] + part[3][le])) + dg[le] + gd;
      double l2 = (double)base + cqs;
      logits[e0 + le] = l2;
      atomicMax(&menc[edA.y], enc64(l2));
    }
  }
  {
    int le = gg * 2 + 1;
    float gd = (GB0.x + h0.x) * JB0.x + (GB0.y + h0.y) * JB0.y
             + (GB0.z + h0.z) * JB0.z + (GB0.w + h0.w) * JB0.w
             + (GB1.x + h1.x) * JB1.x + (GB1.y + h1.y) * JB1.y
             + (GB1.z + h1.z) * JB1.z + (GB1.w + h1.w) * JB1.w
             + i0.x * IB0.x + i0.y * IB0.y + i0.z * IB0.z + i0.w * IB0.w
             + i1.x * IB1.x + i1.y * IB1.y + i1.z * IB1.z + i1.w * IB1.w;
    gd += __shfl_xor(gd, 1, 64);
    gd += __shfl_xor(gd, 2, 64);
    gd += __shfl_xor(gd, 4, 64);
    gd += __shfl_xor(gd, 8, 64);
    if (ll == 0) {
      float base = ((part[0][le] + part[1][le]) + (part[2][le] + part[3][le])) + dg[le] + gd;
      double l2 = (double)base + cqs;
      logits[e0 + le] = l2;
      atomicMax(&menc[edB.y], enc64(l2));
    }
  }
}

// ---------------- exp + segment sum (f64) + zero agg (merged) ----------------
__global__ void k_exp(const int* __restrict__ vi32, const ull* __restrict__ menc,
                      const double* __restrict__ logits, double* __restrict__ ex,
                      double* __restrict__ s, float4* __restrict__ agg) {
  int i = blockIdx.x * 256 + threadIdx.x;
  int st = gridDim.x * 256;
  for (int e = i; e < EE; e += st) {
    int vi = vi32[e];
    double m = dec64(menc[vi]);
    double v = exp(logits[e] - m);
    ex[e] = v;
    atomicAdd(&s[vi], v);
  }
  const int n4 = NN * 32;
  for (int n = i; n < n4; n += st) agg[n] = make_float4(0.f, 0.f, 0.f, 0.f);
}

// ---------------- top-20 per query: per-wave top20 (shfl only) + wave-0 merge ----------------
__global__ void k_topk(const double* __restrict__ ex, const double* __restrict__ s,
                       const float* __restrict__ nscore, const int4* __restrict__ evi,
                       const float* __restrict__ nrep, float* __restrict__ out_score,
                       float* __restrict__ agg, float* __restrict__ appears) {
  int b = blockIdx.x, t = threadIdx.x;  // 256 threads
  int e = b * 256 + t;
  int vi_t = evi[e].y;
  double v = ex[e] / s[vi_t] * (double)nscore[vi_t];
  __shared__ double cv[80];
  __shared__ int ci[80];
  __shared__ int winners[KTOP];
  int w = t >> 6;
  for (int k = 0; k < KTOP; k++) {
    double bv = v;
    int bi = t;
    for (int off = 32; off; off >>= 1) {
      double ov = __shfl_down(bv, off, 64);
      int oi = __shfl_down(bi, off, 64);
      if (ov > bv || (ov == bv && oi < bi)) { bv = ov; bi = oi; }
    }
    bi = __shfl(bi, 0, 64);
    if ((t & 63) == 0) { cv[w * KTOP + k] = bv; ci[w * KTOP + k] = bi; }
    if (t == bi) v = -1.0;
  }
  __syncthreads();
  if (t < 64) {
    double v0 = cv[t];
    int i0 = ci[t];
    double v1 = (t < 16) ? cv[64 + t] : -2.0;
    int i1 = (t < 16) ? ci[64 + t] : (1 << 30);
    for (int k = 0; k < KTOP; k++) {
      double bv; int bi;
      if (v1 > v0 || (v1 == v0 && i1 < i0)) { bv = v1; bi = i1; }
      else                                  { bv = v0; bi = i0; }
      for (int off = 32; off; off >>= 1) {
        double ov = __shfl_down(bv, off, 64);
        int oi = __shfl_down(bi, off, 64);
        if (ov > bv || (ov == bv && oi < bi)) { bv = ov; bi = oi; }
      }
      bi = __shfl(bi, 0, 64);
      if (t == 0) winners[k] = bi;
      if (i0 == bi) v0 = -2.0;
      if (i1 == bi) v1 = -2.0;
    }
  }
  __syncthreads();
  for (int k = 0; k < KTOP; k++) {
    int we = b * 256 + winners[k];
    int4 ew = evi[we];
    int vi = ew.y, vj = ew.z;
    double sm = ex[we] / s[vi];
    if (t < 128) {
      atomicAdd(&agg[(size_t)vi * 128 + t], (float)sm * nrep[(size_t)vj * 128 + t]);
    } else if (t == 128) {
      atomicAdd(&out_score[vj], (float)(sm * (double)nscore[vi]));
    } else if (t == 129) {
      appears[vi] = 1.f;
    }
  }
}

// ---------------- final: leaky_relu((agg + coef*h) @ W_lin^T + b) via MFMA ----------------
__global__ __launch_bounds__(512) void k_final(const float* __restrict__ agg,
                                               const float* __restrict__ appears,
                                               const float* __restrict__ nrep,
                                               const short* __restrict__ Wl_hi,
                                               const short* __restrict__ Wl_lo,
                                               const float* __restrict__ bl,
                                               float* __restrict__ outr) {
  __shared__ __align__(16) float Xs[64][132];
  __shared__ __align__(16) short Bh[16384];
  int t = threadIdx.x;
  int row0 = blockIdx.x * 64;
  int w = t >> 6, l = t & 63;
  int rt = w & 3;
  int c0 = (w >> 2) * 4;
  bf16x8 blv[4][4];
#pragma unroll
  for (int cc = 0; cc < 4; cc++)
#pragma unroll
    for (int kt = 0; kt < 4; kt++)
      blv[cc][kt] = *(const bf16x8*)(Wl_lo + (((c0 + cc) * 4 + kt) * 64 + l) * 8);
#pragma unroll
  for (int i = 0; i < 4; i++) {
    int fi = t + i * 512;
    int r = fi >> 5, c4 = (fi & 31) * 4;
    int rr = row0 + r;
    float4 v = make_float4(0.f, 0.f, 0.f, 0.f);
    if (rr < NN) {
      float4 ag = *(const float4*)(agg + (size_t)rr * 128 + c4);
      float4 h = *(const float4*)(nrep + (size_t)rr * 128 + c4);
      float coef = (appears[rr] > 0.f) ? 0.f : 1.f;
      v.x = ag.x + coef * h.x;
      v.y = ag.y + coef * h.y;
      v.z = ag.z + coef * h.z;
      v.w = ag.w + coef * h.w;
    }
    *(float4*)&Xs[r][c4] = v;
    *(bf16x8*)&Bh[fi * 8] = *(const bf16x8*)(Wl_hi + fi * 8);
  }
  __syncthreads();
  int rloc = rt * 16 + (l & 15);
  int kq = (l >> 4) * 8;
  f32x4 acc[4];
#pragma unroll
  for (int cc = 0; cc < 4; cc++)
#pragma unroll
    for (int j = 0; j < 4; j++) acc[cc][j] = 0.f;
#pragma unroll
  for (int kt = 0; kt < 4; kt++) {
    int kb = kt * 32 + kq;
    float4 x = *(const float4*)&Xs[rloc][kb];
    float4 y = *(const float4*)&Xs[rloc][kb + 4];
    bf16x8 ah, al;
    cvt8(x, y, ah, al);
#pragma unroll
    for (int cc = 0; cc < 4; cc++) {
      int off = (((c0 + cc) * 4 + kt) * 64 + l) * 8;
      bf16x8 bhv = *(const bf16x8*)&Bh[off];
      acc[cc] = __builtin_amdgcn_mfma_f32_16x16x32_bf16(ah, bhv, acc[cc], 0, 0, 0);
      acc[cc] = __builtin_amdgcn_mfma_f32_16x16x32_bf16(al, bhv, acc[cc], 0, 0, 0);
      acc[cc] = __builtin_amdgcn_mfma_f32_16x16x32_bf16(ah, blv[cc][kt], acc[cc], 0, 0, 0);
    }
  }
  __syncthreads();
#pragma unroll
  for (int cc = 0; cc < 4; cc++) {
    int col = (c0 + cc) * 16 + (l & 15);
#pragma unroll
    for (int reg = 0; reg < 4; reg++)
      Xs[rt * 16 + (l >> 4) * 4 + reg][col] = acc[cc][reg];
  }
  __syncthreads();
#pragma unroll
  for (int i = 0; i < 4; i++) {
    int fi = t + i * 512;
    int r = fi >> 5, c4 = (fi & 31) * 4;
    int rr = row0 + r;
    if (rr < NN) {
      float4 v = *(float4*)&Xs[r][c4];
      float4 bb = *(const float4*)&bl[c4];
      float4 o;
      o.x = v.x + bb.x; o.x = (o.x > 0.f) ? o.x : 0.01f * o.x;
      o.y = v.y + bb.y; o.y = (o.y > 0.f) ? o.y : 0.01f * o.y;
      o.z = v.z + bb.z; o.z = (o.z > 0.f) ? o.z : 0.01f * o.z;
      o.w = v.w + bb.w; o.w = (o.w > 0.f) ? o.w : 0.01f * o.w;
      *(float4*)&outr[(size_t)rr * 128 + c4] = o;
    }
  }
}

extern "C" void kernel_launch(void* const* d_in, const int* in_sizes, int n_in,
                              void* d_out, int out_size, void* d_ws, size_t ws_size,
                              hipStream_t stream) {
  const float* node_score = (const float*)d_in[0];
  const float* node_repr  = (const float*)d_in[1];
  const float* rel_emb    = (const float*)d_in[2];
  const float* q_src      = (const float*)d_in[3];
  const float* q_rel      = (const float*)d_in[4];
  const float* Wq         = (const float*)d_in[5];
  const float* Wk         = (const float*)d_in[6];
  const float* W_lin      = (const float*)d_in[7];
  const float* b_lin      = (const float*)d_in[8];
  const int*   edges      = (const int*)d_in[9];

  char* ws = (char*)d_ws;
  size_t off = 0;
  auto carve = [&](size_t bytes) -> void* {
    void* p = ws + off;
    off += (bytes + 255) & ~(size_t)255;
    return p;
  };
  float*  M      = (float*)carve(512 * 512 * 4);
  float*  MT     = (float*)carve(512 * 512 * 4);
  short*  wn_hi  = (short*)carve(3 * 16384 * 2);
  short*  wn_lo  = (short*)carve(3 * 16384 * 2);
  short*  m11_hi = (short*)carve(16384 * 2);
  short*  m11_lo = (short*)carve(16384 * 2);
  short*  wl_hi  = (short*)carve(16384 * 2);
  short*  wl_lo  = (short*)carve(16384 * 2);
  float*  Qv     = (float*)carve((size_t)BQ * 384 * 4);
  double* cq     = (double*)carve((size_t)BQ * 8);
  double* logits = (double*)carve((size_t)EE * 8);
  ull*    menc   = (ull*)carve((size_t)NN * 8);
  double* s      = (double*)carve((size_t)NN * 8);
  double* ex     = (double*)carve((size_t)EE * 8);
  float*  appears= (float*)carve((size_t)NN * 4);
  int4*   evi    = (int4*)carve((size_t)EE * 16);
  int*    vi32   = (int*)carve((size_t)EE * 4);
  float*  PV     = (float*)carve((size_t)NN * 384 * 4);  // [G|H1|nrep] per node
  float*  J      = (float*)carve((size_t)NN * 128 * 4);
  float*  agg    = PV;  // alias: PV dead after k_edge; zeroed inside k_exp

  float* out_score = (float*)d_out;
  float* out_repr  = (float*)d_out + NN;

  k_prep<<<1024, 256, 0, stream>>>(edges, evi, vi32, menc, s, appears, out_score);
  k_matM<<<dim3(512, 2), 256, 0, stream>>>(Wq, Wk, M, MT);
  k_pack<<<320, 256, 0, stream>>>(M, MT, W_lin, wn_hi, wn_lo, m11_hi, m11_lo, wl_hi, wl_lo);
  k_pq<<<BQ, 128, 0, stream>>>(M, MT, q_src, q_rel, Qv, cq);
  k_gemm_node<<<1563, 512, 0, stream>>>(node_repr, wn_hi, wn_lo, PV, J);
  k_edge<<<4096, 512, 0, stream>>>(rel_emb, m11_hi, m11_lo, evi, PV, J, node_repr, Qv, cq, logits, menc);
  k_exp<<<2048, 256, 0, stream>>>(vi32, menc, logits, ex, s, (float4*)agg);
  k_topk<<<BQ, 256, 0, stream>>>(ex, s, node_score, evi, node_repr, out_score, agg, appears);
  k_final<<<1563, 512, 0, stream>>>(agg, appears, node_repr, wl_hi, wl_lo, b_lin, out_repr);
}

// Round 17
// 368.801 us; speedup vs baseline: 1.2377x; 1.2377x over previous
//
#include <hip/hip_runtime.h>

#define NN 100000
#define BQ 1024
#define EE 262144
#define KTOP 20

typedef unsigned long long ull;
typedef __attribute__((ext_vector_type(8))) short bf16x8;
typedef __attribute__((ext_vector_type(4))) float f32x4;

__device__ __forceinline__ ull enc64(double d) {
  ull u = (ull)__double_as_longlong(d);
  return (u >> 63) ? ~u : (u | 0x8000000000000000ull);
}
__device__ __forceinline__ double dec64(ull u) {
  ull b = (u >> 63) ? (u & 0x7FFFFFFFFFFFFFFFull) : ~u;
  return __longlong_as_double((long long)b);
}

__device__ __forceinline__ unsigned short f2bf(float f) {
  unsigned u = __float_as_uint(f);
  u += 0x7fff + ((u >> 16) & 1);
  return (unsigned short)(u >> 16);
}
__device__ __forceinline__ float bf2f(unsigned short h) {
  return __uint_as_float(((unsigned)h) << 16);
}
__device__ __forceinline__ void cvt8(float4 x, float4 y, bf16x8& hi, bf16x8& lo) {
  float a[8] = {x.x, x.y, x.z, x.w, y.x, y.y, y.z, y.w};
#pragma unroll
  for (int j = 0; j < 8; j++) {
    unsigned short h = f2bf(a[j]);
    float r = a[j] - bf2f(h);
    hi[j] = (short)h;
    lo[j] = (short)f2bf(r);
  }
}

// ---------------- init + edge pack (merged) ----------------
__global__ void k_prep(const int* __restrict__ edges, int4* __restrict__ evi,
                       int* __restrict__ vi32, ull* __restrict__ menc,
                       double* __restrict__ s, float* __restrict__ appears,
                       float* __restrict__ out_score) {
  int i = blockIdx.x * 256 + threadIdx.x;
  int st = gridDim.x * 256;
  for (int e = i; e < EE; e += st) {
    int vi = edges[(size_t)e * 8 + 6];
    evi[e] = make_int4(edges[(size_t)e * 8 + 0], vi, edges[(size_t)e * 8 + 7], 0);
    vi32[e] = vi;
  }
  for (int n = i; n < NN; n += st) {
    menc[n] = 0ull;
    s[n] = 0.0;
    appears[n] = 0.f;
    out_score[n] = 0.f;
  }
}

// ---------------- M = Wq^T Wk (f32) + transpose fused ----------------
__global__ void k_matM(const float* __restrict__ Wq, const float* __restrict__ Wk,
                       float* __restrict__ M, float* __restrict__ MT) {
  int x = blockIdx.x;
  int y = blockIdx.y * 256 + threadIdx.x;
  float acc = 0.f;
  for (int a = 0; a < 512; a++)
    acc += Wq[a * 512 + x] * Wk[a * 512 + y];
  M[x * 512 + y] = acc;
  MT[y * 512 + x] = acc;
}

// ---------------- pack B operands as bf16 hi/lo in FRAGMENT ORDER ----------------
__global__ void k_pack(const float* __restrict__ M, const float* __restrict__ MT,
                       const float* __restrict__ Wl,
                       short* __restrict__ wn_hi, short* __restrict__ wn_lo,
                       short* __restrict__ m11_hi, short* __restrict__ m11_lo,
                       short* __restrict__ wl_hi, short* __restrict__ wl_lo) {
  int idx = blockIdx.x * 256 + threadIdx.x;
  if (idx >= 5 * 16384) return;
  int arr = idx >> 14;
  int j16 = idx & 16383;
  int g = j16 >> 9;
  int l = (j16 >> 3) & 63;
  int jj = j16 & 7;
  int c = (g >> 2) * 16 + (l & 15);
  int k = (g & 3) * 32 + ((l >> 4) << 3) + jj;
  float v;
  short *dh, *dl;
  if (arr == 0)      { v = MT[(size_t)c * 512 + k];               dh = wn_hi;          dl = wn_lo; }
  else if (arr == 1) { v = MT[(size_t)(128 + c) * 512 + k];       dh = wn_hi + 16384;  dl = wn_lo + 16384; }
  else if (arr == 2) { v = M[(size_t)(128 + c) * 512 + k];        dh = wn_hi + 32768;  dl = wn_lo + 32768; }
  else if (arr == 3) { v = MT[(size_t)(128 + c) * 512 + 128 + k]; dh = m11_hi;         dl = m11_lo; }
  else               { v = Wl[(size_t)c * 128 + k];               dh = wl_hi;          dl = wl_lo; }
  unsigned short h = f2bf(v);
  float r = v - bf2f(h);
  dh[j16] = (short)h;
  dl[j16] = (short)f2bf(r);
}

// ---------------- per-query vectors (f32) ----------------
__global__ void k_pq(const float* __restrict__ M, const float* __restrict__ MT,
                     const float* __restrict__ qsA, const float* __restrict__ qrA,
                     float* __restrict__ Qv, double* __restrict__ cq) {
  int b = blockIdx.x, d = threadIdx.x;  // 128 threads
  __shared__ float qs[128], qr[128];
  qs[d] = qsA[b * 128 + d];
  qr[d] = qrA[b * 128 + d];
  __syncthreads();
  float uh = 0, ui = 0, ur = 0;
  for (int x = 0; x < 128; x++) {
    float qsx = qs[x], qrx = qr[x];
    uh += qsx * M[(256 + x) * 512 + d]        + qrx * M[(384 + x) * 512 + d];
    ur += qsx * M[(256 + x) * 512 + 128 + d]  + qrx * M[(384 + x) * 512 + 128 + d];
    ui += qsx * MT[(256 + x) * 512 + d]       + qrx * MT[(384 + x) * 512 + d];
    ur += qsx * MT[(256 + x) * 512 + 128 + d] + qrx * MT[(384 + x) * 512 + 128 + d];
  }
  Qv[b * 384 + d]       = uh;
  Qv[b * 384 + 128 + d] = ui;
  Qv[b * 384 + 256 + d] = ur;
  float t1 = 0, t2 = 0;
  for (int y = 0; y < 128; y++) {
    float qsy = qs[y], qry = qr[y];
    t1 += qsy * MT[(256 + y) * 512 + 256 + d] + qry * MT[(384 + y) * 512 + 256 + d];
    t2 += qsy * MT[(256 + y) * 512 + 384 + d] + qry * MT[(384 + y) * 512 + 384 + d];
  }
  float cp = qs[d] * t1 + qr[d] * t2;
  for (int off = 32; off; off >>= 1) cp += __shfl_down(cp, off, 64);
  __shared__ float red[2];
  if ((d & 63) == 0) red[d >> 6] = cp;
  __syncthreads();
  if (d == 0) cq[b] = (double)(red[0] + red[1]);
}

// ---------------- node transforms: one block per 64-row tile, 3-panel loop -> G,H1,J ----------------
__global__ __launch_bounds__(512) void k_gemm_node(const float* __restrict__ A,
                                                   const short* __restrict__ WT_hi,
                                                   const short* __restrict__ WT_lo,
                                                   float* __restrict__ G,
                                                   float* __restrict__ H1,
                                                   float* __restrict__ J) {
  __shared__ __align__(16) float As[64][132];
  __shared__ __align__(16) short Bh[16384];
  float* Of = (float*)Bh;  // output staging view [64][128]
  int t = threadIdx.x;
  int row0 = blockIdx.x * 64;
  int w = t >> 6, l = t & 63;
  int rt = w & 3;
  int c0 = (w >> 2) * 4;
#pragma unroll
  for (int i = 0; i < 4; i++) {
    int fi = t + i * 512;
    int r = fi >> 5, c4 = (fi & 31) * 4;
    float4 v = make_float4(0.f, 0.f, 0.f, 0.f);
    if (row0 + r < NN) v = *(const float4*)(A + (size_t)(row0 + r) * 128 + c4);
    *(float4*)&As[r][c4] = v;
    *(bf16x8*)&Bh[fi * 8] = *(const bf16x8*)(WT_hi + fi * 8);
  }
  __syncthreads();
  int rloc = rt * 16 + (l & 15);
  int kq = (l >> 4) * 8;
  for (int panel = 0; panel < 3; panel++) {
    const short* sl = WT_lo + panel * 16384;
    bf16x8 blv[4][4];
#pragma unroll
    for (int cc = 0; cc < 4; cc++)
#pragma unroll
      for (int kt = 0; kt < 4; kt++)
        blv[cc][kt] = *(const bf16x8*)(sl + (((c0 + cc) * 4 + kt) * 64 + l) * 8);
    f32x4 acc[4];
#pragma unroll
    for (int cc = 0; cc < 4; cc++)
#pragma unroll
      for (int j = 0; j < 4; j++) acc[cc][j] = 0.f;
#pragma unroll
    for (int kt = 0; kt < 4; kt++) {
      int kb = kt * 32 + kq;
      float4 x = *(const float4*)&As[rloc][kb];
      float4 y = *(const float4*)&As[rloc][kb + 4];
      bf16x8 ah, al;
      cvt8(x, y, ah, al);
#pragma unroll
      for (int cc = 0; cc < 4; cc++) {
        int off = (((cc + c0) * 4 + kt) * 64 + l) * 8;
        bf16x8 bhv = *(const bf16x8*)&Bh[off];
        acc[cc] = __builtin_amdgcn_mfma_f32_16x16x32_bf16(ah, bhv, acc[cc], 0, 0, 0);
        acc[cc] = __builtin_amdgcn_mfma_f32_16x16x32_bf16(al, bhv, acc[cc], 0, 0, 0);
        acc[cc] = __builtin_amdgcn_mfma_f32_16x16x32_bf16(ah, blv[cc][kt], acc[cc], 0, 0, 0);
      }
    }
    __syncthreads();
#pragma unroll
    for (int cc = 0; cc < 4; cc++) {
      int col = (c0 + cc) * 16 + (l & 15);
#pragma unroll
      for (int reg = 0; reg < 4; reg++)
        Of[(rt * 16 + (l >> 4) * 4 + reg) * 128 + col] = acc[cc][reg];
    }
    __syncthreads();
    float* dst = (panel == 0) ? G : (panel == 1) ? H1 : J;
#pragma unroll
    for (int i = 0; i < 4; i++) {
      int fi = t + i * 512;
      int r = fi >> 5, c4 = (fi & 31) * 4;
      int rr = row0 + r;
      if (rr < NN) *(float4*)&dst[(size_t)rr * 128 + c4] = *(float4*)&Of[r * 128 + c4];
    }
    if (panel < 2) {
      __syncthreads();
      const short* sh = WT_hi + (panel + 1) * 16384;
#pragma unroll
      for (int i = 0; i < 4; i++) {
        int fi = t + i * 512;
        *(bf16x8*)&Bh[fi * 8] = *(const bf16x8*)(sh + fi * 8);
      }
      __syncthreads();
    }
  }
}

// ---------------- FUSED per-edge kernel: full logit + segment max ----------------
__global__ __launch_bounds__(512, 1) void k_edge(const float* __restrict__ rel,
                                                 const short* __restrict__ M11T_hi,
                                                 const short* __restrict__ M11T_lo,
                                                 const int4* __restrict__ evi,
                                                 const float* __restrict__ H1,
                                                 const float* __restrict__ J,
                                                 const float* __restrict__ G,
                                                 const float* __restrict__ nrep,
                                                 const float* __restrict__ Qv,
                                                 const double* __restrict__ cq,
                                                 double* __restrict__ logits,
                                                 ull* __restrict__ menc) {
  __shared__ __align__(16) float Rs[64][132];
  __shared__ __align__(16) short Bh[16384];
  __shared__ float part[4][64];
  __shared__ float dg[64];
  __shared__ float uhs[128], uis[128], urs[128];
  __shared__ double cqs;
  int t = threadIdx.x;
  int e0 = blockIdx.x * 64;
  int eg = e0 >> 8;  // DEG=256
  int w = t >> 6, l = t & 63;
  int cq2 = w & 3;   // col quarter: col-tiles 2*cq2, 2*cq2+1
  int rh = w >> 2;   // row half: row-tiles 2*rh, 2*rh+1
  // ---- early gather prefetch: H1[vi], J[vj] for 2 edges per 16-lane group ----
  int gg = t >> 4, ll = t & 15, d = ll * 8;
  int4 edA = evi[e0 + gg * 2];
  int4 edB = evi[e0 + gg * 2 + 1];
  const float* pA1 = H1 + (size_t)edA.y * 128 + d;
  const float* pA2 = J + (size_t)edA.z * 128 + d;
  const float* pB1 = H1 + (size_t)edB.y * 128 + d;
  const float* pB2 = J + (size_t)edB.z * 128 + d;
  float4 Aa0 = *(const float4*)pA1, Aa1 = *(const float4*)(pA1 + 4);
  float4 Ab0 = *(const float4*)pA2, Ab1 = *(const float4*)(pA2 + 4);
  float4 Ba0 = *(const float4*)pB1, Ba1 = *(const float4*)(pB1 + 4);
  float4 Bb0 = *(const float4*)pB2, Bb1 = *(const float4*)(pB2 + 4);
  // ---- B-lo register preload (32 VGPRs) ----
  bf16x8 blv[2][4];
#pragma unroll
  for (int cc = 0; cc < 2; cc++)
#pragma unroll
    for (int kt = 0; kt < 4; kt++)
      blv[cc][kt] = *(const bf16x8*)(M11T_lo + (((cq2 * 2 + cc) * 4 + kt) * 64 + l) * 8);
  // ---- stage Rs + Bh + query vectors ----
#pragma unroll
  for (int i = 0; i < 4; i++) {
    int fi = t + i * 512;
    int r = fi >> 5, c4 = (fi & 31) * 4;
    *(float4*)&Rs[r][c4] = *(const float4*)(rel + (size_t)(e0 + r) * 128 + c4);
    *(bf16x8*)&Bh[fi * 8] = *(const bf16x8*)(M11T_hi + fi * 8);
  }
  if (t < 128) {
    uhs[t] = Qv[(size_t)eg * 384 + t];
    uis[t] = Qv[(size_t)eg * 384 + 128 + t];
    urs[t] = Qv[(size_t)eg * 384 + 256 + t];
  }
  if (t == 0) cqs = cq[eg];
  __syncthreads();
  int kq = (l >> 4) * 8;
  int rq4 = (l >> 4) * 4;
  // ---- MFMA phase: 2 row-tiles sequential, B reused ----
#pragma unroll
  for (int rt2 = 0; rt2 < 2; rt2++) {
    int rt = rh * 2 + rt2;
    int rloc = rt * 16 + (l & 15);
    f32x4 acc[2];
#pragma unroll
    for (int cc = 0; cc < 2; cc++)
#pragma unroll
      for (int j = 0; j < 4; j++) acc[cc][j] = 0.f;
#pragma unroll
    for (int kt = 0; kt < 4; kt++) {
      int kb = kt * 32 + kq;
      float4 x = *(const float4*)&Rs[rloc][kb];
      float4 y = *(const float4*)&Rs[rloc][kb + 4];
      bf16x8 ah, al;
      cvt8(x, y, ah, al);
#pragma unroll
      for (int cc = 0; cc < 2; cc++) {
        bf16x8 bhv = *(const bf16x8*)&Bh[(((cq2 * 2 + cc) * 4 + kt) * 64 + l) * 8];
        acc[cc] = __builtin_amdgcn_mfma_f32_16x16x32_bf16(ah, bhv, acc[cc], 0, 0, 0);
        acc[cc] = __builtin_amdgcn_mfma_f32_16x16x32_bf16(al, bhv, acc[cc], 0, 0, 0);
        acc[cc] = __builtin_amdgcn_mfma_f32_16x16x32_bf16(ah, blv[cc][kt], acc[cc], 0, 0, 0);
      }
    }
    float p[4] = {0.f, 0.f, 0.f, 0.f};
#pragma unroll
    for (int cc = 0; cc < 2; cc++) {
      int c = (cq2 * 2 + cc) * 16 + (l & 15);
#pragma unroll
      for (int reg = 0; reg < 4; reg++)
        p[reg] += acc[cc][reg] * Rs[rt * 16 + rq4 + reg][c];
    }
#pragma unroll
    for (int reg = 0; reg < 4; reg++) {
      p[reg] += __shfl_xor(p[reg], 1, 64);
      p[reg] += __shfl_xor(p[reg], 2, 64);
      p[reg] += __shfl_xor(p[reg], 4, 64);
      p[reg] += __shfl_xor(p[reg], 8, 64);
    }
    if ((l & 15) == 0) {
#pragma unroll
      for (int reg = 0; reg < 4; reg++) part[cq2][rt * 16 + rq4 + reg] = p[reg];
    }
  }
  // ---- dg dots using prefetched H1/J ----
  float4 u0 = *(const float4*)&urs[d], u1 = *(const float4*)&urs[d + 4];
  {
    int le = gg * 2;
    float4 r0 = *(const float4*)&Rs[le][d], r1 = *(const float4*)&Rs[le][d + 4];
    float dot = (Aa0.x + Ab0.x + u0.x) * r0.x + (Aa0.y + Ab0.y + u0.y) * r0.y
              + (Aa0.z + Ab0.z + u0.z) * r0.z + (Aa0.w + Ab0.w + u0.w) * r0.w
              + (Aa1.x + Ab1.x + u1.x) * r1.x + (Aa1.y + Ab1.y + u1.y) * r1.y
              + (Aa1.z + Ab1.z + u1.z) * r1.z + (Aa1.w + Ab1.w + u1.w) * r1.w;
    dot += __shfl_xor(dot, 1, 64);
    dot += __shfl_xor(dot, 2, 64);
    dot += __shfl_xor(dot, 4, 64);
    dot += __shfl_xor(dot, 8, 64);
    if (ll == 0) dg[le] = dot;
  }
  {
    int le = gg * 2 + 1;
    float4 r0 = *(const float4*)&Rs[le][d], r1 = *(const float4*)&Rs[le][d + 4];
    float dot = (Ba0.x + Bb0.x + u0.x) * r0.x + (Ba0.y + Bb0.y + u0.y) * r0.y
              + (Ba0.z + Bb0.z + u0.z) * r0.z + (Ba0.w + Bb0.w + u0.w) * r0.w
              + (Ba1.x + Bb1.x + u1.x) * r1.x + (Ba1.y + Bb1.y + u1.y) * r1.y
              + (Ba1.z + Bb1.z + u1.z) * r1.z + (Ba1.w + Bb1.w + u1.w) * r1.w;
    dot += __shfl_xor(dot, 1, 64);
    dot += __shfl_xor(dot, 2, 64);
    dot += __shfl_xor(dot, 4, 64);
    dot += __shfl_xor(dot, 8, 64);
    if (ll == 0) dg[le] = dot;
  }
  // ---- issue G/nrep gathers BEFORE the barrier (latency hides under other waves) ----
  const float* gA  = G + (size_t)edA.y * 128 + d;
  const float* iA  = nrep + (size_t)edA.y * 128 + d;
  const float* jA  = nrep + (size_t)edA.z * 128 + d;
  const float* gB  = G + (size_t)edB.y * 128 + d;
  const float* iB  = nrep + (size_t)edB.y * 128 + d;
  const float* jB  = nrep + (size_t)edB.z * 128 + d;
  float4 GA0 = *(const float4*)gA, GA1 = *(const float4*)(gA + 4);
  float4 IA0 = *(const float4*)iA, IA1 = *(const float4*)(iA + 4);
  float4 JA0 = *(const float4*)jA, JA1 = *(const float4*)(jA + 4);
  float4 GB0 = *(const float4*)gB, GB1 = *(const float4*)(gB + 4);
  float4 IB0 = *(const float4*)iB, IB1 = *(const float4*)(iB + 4);
  float4 JB0 = *(const float4*)jB, JB1 = *(const float4*)(jB + 4);
  __syncthreads();
  // ---- final logit assembly ----
  float4 h0 = *(const float4*)&uhs[d], h1 = *(const float4*)&uhs[d + 4];
  float4 i0 = *(const float4*)&uis[d], i1 = *(const float4*)&uis[d + 4];
  {
    int le = gg * 2;
    float gd = (GA0.x + h0.x) * JA0.x + (GA0.y + h0.y) * JA0.y
             + (GA0.z + h0.z) * JA0.z + (GA0.w + h0.w) * JA0.w
             + (GA1.x + h1.x) * JA1.x + (GA1.y + h1.y) * JA1.y
             + (GA1.z + h1.z) * JA1.z + (GA1.w + h1.w) * JA1.w
             + i0.x * IA0.x + i0.y * IA0.y + i0.z * IA0.z + i0.w * IA0.w
             + i1.x * IA1.x + i1.y * IA1.y + i1.z * IA1.z + i1.w * IA1.w;
    gd += __shfl_xor(gd, 1, 64);
    gd += __shfl_xor(gd, 2, 64);
    gd += __shfl_xor(gd, 4, 64);
    gd += __shfl_xor(gd, 8, 64);
    if (ll == 0) {
      float base = ((part[0][le] + part[1][le]) + (part[2][le] + part[3][le])) + dg[le] + gd;
      double l2 = (double)base + cqs;
      logits[e0 + le] = l2;
      atomicMax(&menc[edA.y], enc64(l2));
    }
  }
  {
    int le = gg * 2 + 1;
    float gd = (GB0.x + h0.x) * JB0.x + (GB0.y + h0.y) * JB0.y
             + (GB0.z + h0.z) * JB0.z + (GB0.w + h0.w) * JB0.w
             + (GB1.x + h1.x) * JB1.x + (GB1.y + h1.y) * JB1.y
             + (GB1.z + h1.z) * JB1.z + (GB1.w + h1.w) * JB1.w
             + i0.x * IB0.x + i0.y * IB0.y + i0.z * IB0.z + i0.w * IB0.w
             + i1.x * IB1.x + i1.y * IB1.y + i1.z * IB1.z + i1.w * IB1.w;
    gd += __shfl_xor(gd, 1, 64);
    gd += __shfl_xor(gd, 2, 64);
    gd += __shfl_xor(gd, 4, 64);
    gd += __shfl_xor(gd, 8, 64);
    if (ll == 0) {
      float base = ((part[0][le] + part[1][le]) + (part[2][le] + part[3][le])) + dg[le] + gd;
      double l2 = (double)base + cqs;
      logits[e0 + le] = l2;
      atomicMax(&menc[edB.y], enc64(l2));
    }
  }
}

// ---------------- exp + segment sum (f64) + zero agg (merged) ----------------
__global__ void k_exp(const int* __restrict__ vi32, const ull* __restrict__ menc,
                      const double* __restrict__ logits, double* __restrict__ ex,
                      double* __restrict__ s, float4* __restrict__ agg) {
  int i = blockIdx.x * 256 + threadIdx.x;
  int st = gridDim.x * 256;
  for (int e = i; e < EE; e += st) {
    int vi = vi32[e];
    double m = dec64(menc[vi]);
    double v = exp(logits[e] - m);
    ex[e] = v;
    atomicAdd(&s[vi], v);
  }
  const int n4 = NN * 32;
  for (int n = i; n < n4; n += st) agg[n] = make_float4(0.f, 0.f, 0.f, 0.f);
}

// ---------------- top-20 per query: per-wave top20 (shfl only) + wave-0 merge ----------------
__global__ void k_topk(const double* __restrict__ ex, const double* __restrict__ s,
                       const float* __restrict__ nscore, const int4* __restrict__ evi,
                       const float* __restrict__ nrep, float* __restrict__ out_score,
                       float* __restrict__ agg, float* __restrict__ appears) {
  int b = blockIdx.x, t = threadIdx.x;  // 256 threads
  int e = b * 256 + t;
  int vi_t = evi[e].y;
  double v = ex[e] / s[vi_t] * (double)nscore[vi_t];
  __shared__ double cv[80];
  __shared__ int ci[80];
  __shared__ int winners[KTOP];
  int w = t >> 6;
  for (int k = 0; k < KTOP; k++) {
    double bv = v;
    int bi = t;
    for (int off = 32; off; off >>= 1) {
      double ov = __shfl_down(bv, off, 64);
      int oi = __shfl_down(bi, off, 64);
      if (ov > bv || (ov == bv && oi < bi)) { bv = ov; bi = oi; }
    }
    bi = __shfl(bi, 0, 64);
    if ((t & 63) == 0) { cv[w * KTOP + k] = bv; ci[w * KTOP + k] = bi; }
    if (t == bi) v = -1.0;
  }
  __syncthreads();
  if (t < 64) {
    double v0 = cv[t];
    int i0 = ci[t];
    double v1 = (t < 16) ? cv[64 + t] : -2.0;
    int i1 = (t < 16) ? ci[64 + t] : (1 << 30);
    for (int k = 0; k < KTOP; k++) {
      double bv; int bi;
      if (v1 > v0 || (v1 == v0 && i1 < i0)) { bv = v1; bi = i1; }
      else                                  { bv = v0; bi = i0; }
      for (int off = 32; off; off >>= 1) {
        double ov = __shfl_down(bv, off, 64);
        int oi = __shfl_down(bi, off, 64);
        if (ov > bv || (ov == bv && oi < bi)) { bv = ov; bi = oi; }
      }
      bi = __shfl(bi, 0, 64);
      if (t == 0) winners[k] = bi;
      if (i0 == bi) v0 = -2.0;
      if (i1 == bi) v1 = -2.0;
    }
  }
  __syncthreads();
  for (int k = 0; k < KTOP; k++) {
    int we = b * 256 + winners[k];
    int4 ew = evi[we];
    int vi = ew.y, vj = ew.z;
    double sm = ex[we] / s[vi];
    if (t < 128) {
      atomicAdd(&agg[(size_t)vi * 128 + t], (float)sm * nrep[(size_t)vj * 128 + t]);
    } else if (t == 128) {
      atomicAdd(&out_score[vj], (float)(sm * (double)nscore[vi]));
    } else if (t == 129) {
      appears[vi] = 1.f;
    }
  }
}

// ---------------- final: leaky_relu((agg + coef*h) @ W_lin^T + b) via MFMA ----------------
__global__ __launch_bounds__(512) void k_final(const float* __restrict__ agg,
                                               const float* __restrict__ appears,
                                               const float* __restrict__ nrep,
                                               const short* __restrict__ Wl_hi,
                                               const short* __restrict__ Wl_lo,
                                               const float* __restrict__ bl,
                                               float* __restrict__ outr) {
  __shared__ __align__(16) float Xs[64][132];
  __shared__ __align__(16) short Bh[16384];
  int t = threadIdx.x;
  int row0 = blockIdx.x * 64;
  int w = t >> 6, l = t & 63;
  int rt = w & 3;
  int c0 = (w >> 2) * 4;
  bf16x8 blv[4][4];
#pragma unroll
  for (int cc = 0; cc < 4; cc++)
#pragma unroll
    for (int kt = 0; kt < 4; kt++)
      blv[cc][kt] = *(const bf16x8*)(Wl_lo + (((c0 + cc) * 4 + kt) * 64 + l) * 8);
#pragma unroll
  for (int i = 0; i < 4; i++) {
    int fi = t + i * 512;
    int r = fi >> 5, c4 = (fi & 31) * 4;
    int rr = row0 + r;
    float4 v = make_float4(0.f, 0.f, 0.f, 0.f);
    if (rr < NN) {
      float4 ag = *(const float4*)(agg + (size_t)rr * 128 + c4);
      float4 h = *(const float4*)(nrep + (size_t)rr * 128 + c4);
      float coef = (appears[rr] > 0.f) ? 0.f : 1.f;
      v.x = ag.x + coef * h.x;
      v.y = ag.y + coef * h.y;
      v.z = ag.z + coef * h.z;
      v.w = ag.w + coef * h.w;
    }
    *(float4*)&Xs[r][c4] = v;
    *(bf16x8*)&Bh[fi * 8] = *(const bf16x8*)(Wl_hi + fi * 8);
  }
  __syncthreads();
  int rloc = rt * 16 + (l & 15);
  int kq = (l >> 4) * 8;
  f32x4 acc[4];
#pragma unroll
  for (int cc = 0; cc < 4; cc++)
#pragma unroll
    for (int j = 0; j < 4; j++) acc[cc][j] = 0.f;
#pragma unroll
  for (int kt = 0; kt < 4; kt++) {
    int kb = kt * 32 + kq;
    float4 x = *(const float4*)&Xs[rloc][kb];
    float4 y = *(const float4*)&Xs[rloc][kb + 4];
    bf16x8 ah, al;
    cvt8(x, y, ah, al);
#pragma unroll
    for (int cc = 0; cc < 4; cc++) {
      int off = (((c0 + cc) * 4 + kt) * 64 + l) * 8;
      bf16x8 bhv = *(const bf16x8*)&Bh[off];
      acc[cc] = __builtin_amdgcn_mfma_f32_16x16x32_bf16(ah, bhv, acc[cc], 0, 0, 0);
      acc[cc] = __builtin_amdgcn_mfma_f32_16x16x32_bf16(al, bhv, acc[cc], 0, 0, 0);
      acc[cc] = __builtin_amdgcn_mfma_f32_16x16x32_bf16(ah, blv[cc][kt], acc[cc], 0, 0, 0);
    }
  }
  __syncthreads();
#pragma unroll
  for (int cc = 0; cc < 4; cc++) {
    int col = (c0 + cc) * 16 + (l & 15);
#pragma unroll
    for (int reg = 0; reg < 4; reg++)
      Xs[rt * 16 + (l >> 4) * 4 + reg][col] = acc[cc][reg];
  }
  __syncthreads();
#pragma unroll
  for (int i = 0; i < 4; i++) {
    int fi = t + i * 512;
    int r = fi >> 5, c4 = (fi & 31) * 4;
    int rr = row0 + r;
    if (rr < NN) {
      float4 v = *(float4*)&Xs[r][c4];
      float4 bb = *(const float4*)&bl[c4];
      float4 o;
      o.x = v.x + bb.x; o.x = (o.x > 0.f) ? o.x : 0.01f * o.x;
      o.y = v.y + bb.y; o.y = (o.y > 0.f) ? o.y : 0.01f * o.y;
      o.z = v.z + bb.z; o.z = (o.z > 0.f) ? o.z : 0.01f * o.z;
      o.w = v.w + bb.w; o.w = (o.w > 0.f) ? o.w : 0.01f * o.w;
      *(float4*)&outr[(size_t)rr * 128 + c4] = o;
    }
  }
}

extern "C" void kernel_launch(void* const* d_in, const int* in_sizes, int n_in,
                              void* d_out, int out_size, void* d_ws, size_t ws_size,
                              hipStream_t stream) {
  const float* node_score = (const float*)d_in[0];
  const float* node_repr  = (const float*)d_in[1];
  const float* rel_emb    = (const float*)d_in[2];
  const float* q_src      = (const float*)d_in[3];
  const float* q_rel      = (const float*)d_in[4];
  const float* Wq         = (const float*)d_in[5];
  const float* Wk         = (const float*)d_in[6];
  const float* W_lin      = (const float*)d_in[7];
  const float* b_lin      = (const float*)d_in[8];
  const int*   edges      = (const int*)d_in[9];

  char* ws = (char*)d_ws;
  size_t off = 0;
  auto carve = [&](size_t bytes) -> void* {
    void* p = ws + off;
    off += (bytes + 255) & ~(size_t)255;
    return p;
  };
  float*  M      = (float*)carve(512 * 512 * 4);
  float*  MT     = (float*)carve(512 * 512 * 4);
  short*  wn_hi  = (short*)carve(3 * 16384 * 2);
  short*  wn_lo  = (short*)carve(3 * 16384 * 2);
  short*  m11_hi = (short*)carve(16384 * 2);
  short*  m11_lo = (short*)carve(16384 * 2);
  short*  wl_hi  = (short*)carve(16384 * 2);
  short*  wl_lo  = (short*)carve(16384 * 2);
  float*  Qv     = (float*)carve((size_t)BQ * 384 * 4);
  double* cq     = (double*)carve((size_t)BQ * 8);
  double* logits = (double*)carve((size_t)EE * 8);
  ull*    menc   = (ull*)carve((size_t)NN * 8);
  double* s      = (double*)carve((size_t)NN * 8);
  double* ex     = (double*)carve((size_t)EE * 8);
  float*  appears= (float*)carve((size_t)NN * 4);
  int4*   evi    = (int4*)carve((size_t)EE * 16);
  int*    vi32   = (int*)carve((size_t)EE * 4);
  float*  G      = (float*)carve((size_t)NN * 128 * 4);
  float*  H1     = (float*)carve((size_t)NN * 128 * 4);
  float*  J      = (float*)carve((size_t)NN * 128 * 4);
  float*  agg    = G;  // alias: G dead after k_edge; zeroed inside k_exp

  float* out_score = (float*)d_out;
  float* out_repr  = (float*)d_out + NN;

  k_prep<<<1024, 256, 0, stream>>>(edges, evi, vi32, menc, s, appears, out_score);
  k_matM<<<dim3(512, 2), 256, 0, stream>>>(Wq, Wk, M, MT);
  k_pack<<<320, 256, 0, stream>>>(M, MT, W_lin, wn_hi, wn_lo, m11_hi, m11_lo, wl_hi, wl_lo);
  k_pq<<<BQ, 128, 0, stream>>>(M, MT, q_src, q_rel, Qv, cq);
  k_gemm_node<<<1563, 512, 0, stream>>>(node_repr, wn_hi, wn_lo, G, H1, J);
  k_edge<<<4096, 512, 0, stream>>>(rel_emb, m11_hi, m11_lo, evi, H1, J, G, node_repr, Qv, cq, logits, menc);
  k_exp<<<2048, 256, 0, stream>>>(vi32, menc, logits, ex, s, (float4*)agg);
  k_topk<<<BQ, 256, 0, stream>>>(ex, s, node_score, evi, node_repr, out_score, agg, appears);
  k_final<<<1563, 512, 0, stream>>>(agg, appears, node_repr, wl_hi, wl_lo, b_lin, out_repr);
}